// Round 10
// baseline (402.475 us; speedup 1.0000x reference)
//
#include <hip/hip_runtime.h>
#include <hip/hip_bf16.h>
#include <cstdint>
#include <cstddef>

// ---------------------------------------------------------------------------
// MultiHeadAttention fused pipeline, bf16 MFMA compute.
//   B=4, S=2048, D=1024, H=16, dk=64
// Stages:
//   1. cvt_all: weights fp32->bf16 (activations converted in-GEMM)
//   2. rope tables [S][32]
//   3. gemm_fused<MODE,AF32=1>: QKV projections read fp32 activations,
//      reg-stage+convert A; fused epilogues:
//        0: +bias -> RoPE -> *0.125*log2e -> Qh [bh][s][dk]
//        1: +bias -> RoPE ->                Kh [bh][s][dk]
//        2: +bias -> transpose           -> Vtr [bh][dk][s]
//   4. flash attention (causal, swapped-operand MFMA, LPT-ordered 1024
//      blocks, double-buffered staging, defer-max) -> ctx bf16 [B*S, D]
//   5. gemm_fused<3,0>: out = ctx @ W_o^T + b_o (f32, token-major)
// ---------------------------------------------------------------------------

typedef __attribute__((ext_vector_type(8))) short short8;   // 8 x bf16 (4 VGPR)
typedef __attribute__((ext_vector_type(4))) float f32x4;    // MFMA C/D frag
typedef unsigned short u16;

#define SCALE_Q 0.18033688011112042f   /* 0.125 * log2(e): scores in exp2 domain */

__device__ __forceinline__ u16 f2bf(float f) {
  __hip_bfloat16 h = __float2bfloat16(f);
  return *reinterpret_cast<u16*>(&h);
}
__device__ __forceinline__ float bf2f(short bits) {
  unsigned int u = ((unsigned int)(u16)bits) << 16;
  return __uint_as_float(u);
}
__device__ __forceinline__ void gload_lds16(const void* g, void* l) {
  __builtin_amdgcn_global_load_lds(
      (const __attribute__((address_space(1))) void*)g,
      (__attribute__((address_space(3))) void*)l, 16, 0, 0);
}
__device__ __forceinline__ f32x4 max4(f32x4 a, f32x4 b) {
  f32x4 r;
  r[0] = fmaxf(a[0], b[0]); r[1] = fmaxf(a[1], b[1]);
  r[2] = fmaxf(a[2], b[2]); r[3] = fmaxf(a[3], b[3]);
  return r;
}

// ---------------------------------------------------------------------------
// 1. fp32 -> bf16 convert (weights only now), 4 jobs
// ---------------------------------------------------------------------------
struct CvtJobs {
  const float* src[7];
  u16* dst[7];
  int pref[8];   // prefix sums in float4 units (unused tail = total)
};

__global__ void cvt_all(CvtJobs jobs, int total4) {
  const int stride = gridDim.x * blockDim.x;
  for (int i = blockIdx.x * blockDim.x + threadIdx.x; i < total4; i += stride) {
    int j = 0;
#pragma unroll
    for (int t = 1; t < 7; ++t) j += (i >= jobs.pref[t]);
    const int off = i - jobs.pref[j];
    const float4 v = ((const float4*)jobs.src[j])[off];
    ushort4 o;
    o.x = f2bf(v.x); o.y = f2bf(v.y); o.z = f2bf(v.z); o.w = f2bf(v.w);
    ((ushort4*)jobs.dst[j])[off] = o;
  }
}

// ---------------------------------------------------------------------------
// 2. RoPE tables: cos/sin(s * 10000^(-i/32)), i in [0,32)
// ---------------------------------------------------------------------------
__global__ void rope_tables(float* __restrict__ cost, float* __restrict__ sint, int S) {
  const int idx = blockIdx.x * blockDim.x + threadIdx.x;
  if (idx >= S * 32) return;
  const int s = idx >> 5, i = idx & 31;
  const float invf = powf(10000.0f, -(float)i * (1.0f / 32.0f));
  const float ang = (float)s * invf;
  cost[idx] = cosf(ang);
  sint[idx] = sinf(ang);
}

// ---------------------------------------------------------------------------
// 3/5. GEMM  C = A[M,K] @ Bt[N,K]^T + bias, fused epilogues.
//   AF32=1: A is fp32 -> reg-stage + convert + swizzled ds_write (write-side
//   swizzle matches the swizzled read; B stays global_load_lds with
//   pre-swizzled source). AF32=0: A is bf16 via global_load_lds.
//   MODE 0: Q -> RoPE -> *SCALE_Q -> [bh][s][64]
//   MODE 1: K -> RoPE ->            [bh][s][64]
//   MODE 2: V -> transpose ->       [bh][64][s]
//   MODE 3: f32 token-major [M][N]  (output projection)
//   128x128 tile, BK=64, 4 waves, 16x16x32 MFMA. 1D grid 512, XCD-chunked.
// ---------------------------------------------------------------------------
template<int MODE, int AF32>
__global__ __launch_bounds__(256, 2)
void gemm_fused(const void* __restrict__ Ain, const u16* __restrict__ Bt,
                const float* __restrict__ bias, void* __restrict__ Cout,
                const float* __restrict__ cost, const float* __restrict__ sint,
                int M, int N, int K, int S) {
  __shared__ u16 As[128 * 64];
  __shared__ u16 Bs[128 * 64];
  const u16* A16 = (const u16*)Ain;
  const float* A32 = (const float*)Ain;
  const int tid = threadIdx.x;
  const int wid = tid >> 6;
  const int lane = tid & 63;
  const int g = lane >> 4, c = lane & 15;

  // XCD-chunked remap (hw round-robins linear id over 8 XCDs)
  const int xcd = blockIdx.x & 7;
  const int slot = blockIdx.x >> 3;
  const int mPerX = (M >> 7) >> 3;               // 8
  const int m0 = (xcd * mPerX + (slot % mPerX)) << 7;
  const int n0 = (slot / mPerX) << 7;

  const int wr = wid >> 1, wc = wid & 1;

  f32x4 acc[4][4];
#pragma unroll
  for (int i = 0; i < 4; ++i)
#pragma unroll
    for (int j = 0; j < 4; ++j) acc[i][j] = (f32x4)(0.0f);

  const int kIters = K >> 6;
  for (int kt = 0; kt < kIters; ++kt) {
    const int k0 = kt << 6;
    // B first (async DMA overlaps A reg-staging)
#pragma unroll
    for (int i = 0; i < 4; ++i) {
      const int chunk = i * 256 + tid;
      const int row = chunk >> 3;
      const int scz = (chunk & 7) ^ (row & 7);
      gload_lds16(Bt + (size_t)(n0 + row) * K + (k0 + scz * 8),
                  (char*)Bs + (size_t)(i * 256 + (wid << 6)) * 16);
    }
    if (AF32) {
      // A: fp32 global -> regs -> bf16 -> swizzled ds_write_b128
#pragma unroll
      for (int i = 0; i < 4; ++i) {
        const int chunk = i * 256 + tid;
        const int row = chunk >> 3;
        const int c8 = (chunk & 7) * 8;
        const float* src = A32 + (size_t)(m0 + row) * K + k0 + c8;
        const float4 f0 = *(const float4*)(src);
        const float4 f1 = *(const float4*)(src + 4);
        short8 v;
        v[0] = (short)f2bf(f0.x); v[1] = (short)f2bf(f0.y);
        v[2] = (short)f2bf(f0.z); v[3] = (short)f2bf(f0.w);
        v[4] = (short)f2bf(f1.x); v[5] = (short)f2bf(f1.y);
        v[6] = (short)f2bf(f1.z); v[7] = (short)f2bf(f1.w);
        const int dst = (chunk & 7) ^ (row & 7);
        *(short8*)((char*)As + row * 128 + dst * 16) = v;
      }
    } else {
#pragma unroll
      for (int i = 0; i < 4; ++i) {
        const int chunk = i * 256 + tid;
        const int row = chunk >> 3;
        const int scz = (chunk & 7) ^ (row & 7);
        gload_lds16(A16 + (size_t)(m0 + row) * K + (k0 + scz * 8),
                    (char*)As + (size_t)(i * 256 + (wid << 6)) * 16);
      }
    }
    __syncthreads();
#pragma unroll
    for (int ks = 0; ks < 2; ++ks) {
      short8 af[4], bfr[4];
#pragma unroll
      for (int mi = 0; mi < 4; ++mi) {
        const int row = wr * 64 + mi * 16 + c;
        const int cch = (g + ks * 4) ^ (row & 7);
        af[mi] = *(const short8*)((const char*)As + row * 128 + cch * 16);
      }
#pragma unroll
      for (int ni = 0; ni < 4; ++ni) {
        const int row = wc * 64 + ni * 16 + c;
        const int cch = (g + ks * 4) ^ (row & 7);
        bfr[ni] = *(const short8*)((const char*)Bs + row * 128 + cch * 16);
      }
#pragma unroll
      for (int mi = 0; mi < 4; ++mi)
#pragma unroll
        for (int ni = 0; ni < 4; ++ni)
          acc[mi][ni] = __builtin_amdgcn_mfma_f32_16x16x32_bf16(af[mi], bfr[ni], acc[mi][ni], 0, 0, 0);
    }
    __syncthreads();
  }

  float bv[4];
#pragma unroll
  for (int ni = 0; ni < 4; ++ni) bv[ni] = bias[n0 + wc * 64 + ni * 16 + c];

  // C/D layout: col = lane&15, row = (lane>>4)*4 + reg  [m89/m91 verified]
  if (MODE == 3) {
#pragma unroll
    for (int mi = 0; mi < 4; ++mi)
#pragma unroll
      for (int ni = 0; ni < 4; ++ni)
#pragma unroll
        for (int r = 0; r < 4; ++r) {
          const int row = m0 + wr * 64 + mi * 16 + g * 4 + r;
          const int col = n0 + wc * 64 + ni * 16 + c;
          ((float*)Cout)[(size_t)row * N + col] = acc[mi][ni][r] + bv[ni];
        }
  } else if (MODE == 2) {
    // V: +bias, transpose to [bh][64][S]; 4 consecutive tokens -> ushort4
#pragma unroll
    for (int mi = 0; mi < 4; ++mi) {
      const int row_base = m0 + wr * 64 + mi * 16 + g * 4;
      const int s = row_base & 2047;            // S = 2048
      const int b = row_base >> 11;
#pragma unroll
      for (int ni = 0; ni < 4; ++ni) {
        const int col = n0 + wc * 64 + ni * 16 + c;
        const int h = col >> 6;
        const int d = ni * 16 + c;              // col & 63
        ushort4 w;
        w.x = f2bf(acc[mi][ni][0] + bv[ni]);
        w.y = f2bf(acc[mi][ni][1] + bv[ni]);
        w.z = f2bf(acc[mi][ni][2] + bv[ni]);
        w.w = f2bf(acc[mi][ni][3] + bv[ni]);
        *(ushort4*)((u16*)Cout + ((size_t)(b * 16 + h) * 64 + d) * (size_t)S + s) = w;
      }
    }
  } else {
    // Q/K: +bias, RoPE on pairs (ni, ni+2) == (d, d+32), Q also *SCALE_Q
#pragma unroll
    for (int mi = 0; mi < 4; ++mi)
#pragma unroll
      for (int pair = 0; pair < 2; ++pair) {
        const int d_lo = pair * 16 + c;         // in [0,32) -> freq index i
        const int col_lo = n0 + wc * 64 + d_lo;
        const int h = col_lo >> 6;
#pragma unroll
        for (int r = 0; r < 4; ++r) {
          const int row = m0 + wr * 64 + mi * 16 + g * 4 + r;
          const int s = row & 2047;             // S = 2048
          const int b = row >> 11;
          const float co = cost[s * 32 + d_lo];
          const float si = sint[s * 32 + d_lo];
          const float vlo = acc[mi][pair][r] + bv[pair];
          const float vhi = acc[mi][pair + 2][r] + bv[pair + 2];
          float olo = vlo * co - vhi * si;
          float ohi = vhi * co + vlo * si;
          if (MODE == 0) { olo *= SCALE_Q; ohi *= SCALE_Q; }
          u16* dst = (u16*)Cout + ((size_t)(b * 16 + h) * S + s) * 64 + d_lo;
          dst[0]  = f2bf(olo);
          dst[32] = f2bf(ohi);
        }
      }
  }
}

// ---------------------------------------------------------------------------
// 4. causal flash attention, v4: LPT-ordered independent blocks.
//   1024 blocks, each ONE 128-q supertile. stile = 15 - (id>>6) so the
//   32-tile blocks dispatch FIRST and small ones backfill (LPT makespan,
//   no id->CU mapping assumption — round-8 lesson). bh = id&63 keeps
//   bh&7 == id&7 -> stable head->XCD L2 partition (4MB K/V per XCD).
//   4 waves x 32 q-rows. Swapped-operand MFMA, 2-phase double-buffered
//   staging, defer-max THR=8, setprio around MFMA clusters.
// ---------------------------------------------------------------------------
__global__ __launch_bounds__(256, 4)
void attn_kernel(const u16* __restrict__ Qh, const u16* __restrict__ Kh,
                 const u16* __restrict__ Vt, u16* __restrict__ ctx,
                 int B, int H, int S) {
  __shared__ u16 KV[2][2][64 * 64];   // [buf][K=0/V=1], 32 KiB
  __shared__ u16 Ps[4][16 * 64];      // per-wave P tile (reused per qf), 8 KiB
  const int tid = threadIdx.x, wid = tid >> 6, lane = tid & 63;
  const int g = lane >> 4, c = lane & 15;

  const int id = blockIdx.x;             // 0..1023
  const int stile = 15 - (id >> 6);      // LPT: big stiles first
  const int bh = id & 63;                // bh&7 == id&7 -> XCD partition

  const int b = bh >> 4, h = bh & 15;
  const int D = H * 64;

  const size_t baseQK = (size_t)bh * S * 64;
  const size_t baseV  = (size_t)bh * 64 * S;

  const int q0 = stile * 128;
  const int KT = 2 * stile + 2;          // causal k-tiles for this supertile
  const int q0w = q0 + wid * 32;
  const int ktl = (q0w + 31) >> 6;       // wave's last (partial) k-tile
  const int qg0 = q0w + c, qg1 = q0w + 16 + c;

  // Q B-frags, hoisted: lane holds Q[q0w+qf*16+c][32*ks+8*g .. +8)
  short8 qB[2][2];
#pragma unroll
  for (int qf = 0; qf < 2; ++qf)
#pragma unroll
    for (int ks = 0; ks < 2; ++ks)
      qB[qf][ks] = *(const short8*)(Qh + baseQK +
                     (size_t)(q0w + qf * 16 + c) * 64 + ks * 32 + g * 8);

  float m_r[2], l_r[2];
  m_r[0] = m_r[1] = -__builtin_inff();
  l_r[0] = l_r[1] = 0.0f;
  f32x4 o[4][2];
#pragma unroll
  for (int df = 0; df < 4; ++df) { o[df][0] = (f32x4)(0.0f); o[df][1] = (f32x4)(0.0f); }

  auto stage = [&](int buf, int kt) {
#pragma unroll
    for (int i = 0; i < 2; ++i) {
      const int chunk = i * 256 + tid;
      const int row = chunk >> 3;
      const int scz = (chunk & 7) ^ (row & 7);
      gload_lds16(Kh + baseQK + (size_t)(kt * 64 + row) * 64 + scz * 8,
                  (char*)&KV[buf][0][0] + (size_t)(i * 256 + (wid << 6)) * 16);
      gload_lds16(Vt + baseV + (size_t)row * S + (kt * 64 + scz * 8),
                  (char*)&KV[buf][1][0] + (size_t)(i * 256 + (wid << 6)) * 16);
    }
  };

  stage(0, 0);
  __syncthreads();
  int cur = 0;
  for (int kt = 0; kt < KT; ++kt) {
    if (kt + 1 < KT) stage(cur ^ 1, kt + 1);   // 2-phase prefetch
    if (kt <= ktl) {                            // wave-uniform causal skip
      const char* Kb = (const char*)&KV[cur][0][0];
      const char* Vb = (const char*)&KV[cur][1][0];

      // QK^T (swapped): sc[kf][qf] = D[k=kf*16+4g+r][q=qf*16+c]
      f32x4 sc[4][2];
#pragma unroll
      for (int kf = 0; kf < 4; ++kf) { sc[kf][0] = (f32x4)(0.0f); sc[kf][1] = (f32x4)(0.0f); }
      __builtin_amdgcn_s_setprio(1);
#pragma unroll
      for (int ks = 0; ks < 2; ++ks) {
        short8 kA[4];
#pragma unroll
        for (int kf = 0; kf < 4; ++kf) {
          const int row = kf * 16 + c;
          kA[kf] = *(const short8*)(Kb + row * 128 + (((g + 4 * ks) ^ (row & 7))) * 16);
        }
#pragma unroll
        for (int kf = 0; kf < 4; ++kf) {
          sc[kf][0] = __builtin_amdgcn_mfma_f32_16x16x32_bf16(kA[kf], qB[0][ks], sc[kf][0], 0, 0, 0);
          sc[kf][1] = __builtin_amdgcn_mfma_f32_16x16x32_bf16(kA[kf], qB[1][ks], sc[kf][1], 0, 0, 0);
        }
      }
      __builtin_amdgcn_s_setprio(0);

      if (kt == ktl) {   // only the last tile is causally partial
#pragma unroll
        for (int kf = 0; kf < 4; ++kf)
#pragma unroll
          for (int r = 0; r < 4; ++r) {
            const int kg = kt * 64 + kf * 16 + 4 * g + r;
            if (kg > qg0) sc[kf][0][r] = -__builtin_inff();
            if (kg > qg1) sc[kf][1][r] = -__builtin_inff();
          }
      }

      u16* Pw = &Ps[wid][0];
      short8 pB[2][2];
#pragma unroll
      for (int qf = 0; qf < 2; ++qf) {
        // row max: 15 in-lane + 2 shfl (lanes c,c+16,c+32,c+48 share q)
        f32x4 mm = max4(max4(sc[0][qf], sc[1][qf]), max4(sc[2][qf], sc[3][qf]));
        float pm = fmaxf(fmaxf(mm[0], mm[1]), fmaxf(mm[2], mm[3]));
        pm = fmaxf(pm, __shfl_xor(pm, 16));
        pm = fmaxf(pm, __shfl_xor(pm, 32));
        // defer-max (THR=8 in exp2 domain -> P bounded by 256)
        if (__any(pm > m_r[qf] + 8.0f)) {
          const float mn = fmaxf(m_r[qf], pm);
          const float rs = __builtin_exp2f(m_r[qf] - mn);
          m_r[qf] = mn; l_r[qf] *= rs;
#pragma unroll
          for (int df = 0; df < 4; ++df) o[df][qf] *= rs;
        }
        f32x4 ps4 = (f32x4)(0.0f);
#pragma unroll
        for (int kf = 0; kf < 4; ++kf) {
          f32x4 pv;
#pragma unroll
          for (int r = 0; r < 4; ++r) pv[r] = __builtin_exp2f(sc[kf][qf][r] - m_r[qf]);
          sc[kf][qf] = pv;
          ps4 += pv;
        }
        float psum = (ps4[0] + ps4[1]) + (ps4[2] + ps4[3]);
        psum += __shfl_xor(psum, 16);
        psum += __shfl_xor(psum, 32);
        l_r[qf] += psum;

        // P -> per-wave LDS (b64 writes, swizzled), then P^T B-frags
#pragma unroll
        for (int kf = 0; kf < 4; ++kf) {
          ushort4 pk;
          pk.x = f2bf(sc[kf][qf][0]); pk.y = f2bf(sc[kf][qf][1]);
          pk.z = f2bf(sc[kf][qf][2]); pk.w = f2bf(sc[kf][qf][3]);
          *(ushort4*)((char*)Pw + c * 128 +
                      (((2 * kf + (g >> 1)) ^ (c & 7))) * 16 + 8 * (g & 1)) = pk;
        }
#pragma unroll
        for (int ks = 0; ks < 2; ++ks)
          pB[qf][ks] = *(const short8*)((const char*)Pw + c * 128 +
                                        (((g + 4 * ks) ^ (c & 7))) * 16);
      }

      // PV (swapped): o[df][qf] = D[d=df*16+4g+r][q=qf*16+c]
      __builtin_amdgcn_s_setprio(1);
#pragma unroll
      for (int ks = 0; ks < 2; ++ks)
#pragma unroll
        for (int df = 0; df < 4; ++df) {
          const int row = df * 16 + c;
          const short8 va = *(const short8*)(Vb + row * 128 + (((g + 4 * ks) ^ (row & 7))) * 16);
          o[df][0] = __builtin_amdgcn_mfma_f32_16x16x32_bf16(va, pB[0][ks], o[df][0], 0, 0, 0);
          o[df][1] = __builtin_amdgcn_mfma_f32_16x16x32_bf16(va, pB[1][ks], o[df][1], 0, 0, 0);
        }
      __builtin_amdgcn_s_setprio(0);
    }
    __syncthreads();
    cur ^= 1;
  }

  // epilogue: O^T -> ctx token-major; lane owns rows q (qf*16+c), d runs of 4
#pragma unroll
  for (int qf = 0; qf < 2; ++qf) {
    const float inv = 1.0f / l_r[qf];
    u16* rowp = ctx + (size_t)(b * S + q0w + qf * 16 + c) * D + h * 64;
#pragma unroll
    for (int df = 0; df < 4; ++df) {
      ushort4 w;
      w.x = f2bf(o[df][qf][0] * inv); w.y = f2bf(o[df][qf][1] * inv);
      w.z = f2bf(o[df][qf][2] * inv); w.w = f2bf(o[df][qf][3] * inv);
      *(ushort4*)(rowp + df * 16 + 4 * g) = w;
    }
  }
}

// ---------------------------------------------------------------------------
extern "C" void kernel_launch(void* const* d_in, const int* in_sizes, int n_in,
                              void* d_out, int out_size, void* d_ws, size_t ws_size,
                              hipStream_t stream) {
  const float* query = (const float*)d_in[0];
  const float* key   = (const float*)d_in[1];
  const float* value = (const float*)d_in[2];
  const float* W_q = (const float*)d_in[3];
  const float* b_q = (const float*)d_in[4];
  const float* W_k = (const float*)d_in[5];
  const float* b_k = (const float*)d_in[6];
  const float* W_v = (const float*)d_in[7];
  const float* b_v = (const float*)d_in[8];
  const float* W_o = (const float*)d_in[9];
  const float* b_o = (const float*)d_in[10];

  const int D = 1024, H = 16, S = 2048;
  const int BS = in_sizes[0] / D;          // B * S = 8192
  const int B = BS / S;

  const size_t nX = (size_t)BS * D;        // 8.4M elems
  const size_t nW = (size_t)D * D;
  u16* p = (u16*)d_ws;
  u16* ctx = p; p += nX;
  u16* wq = p;  p += nW;
  u16* wk = p;  p += nW;
  u16* wv = p;  p += nW;
  u16* wo = p;  p += nW;
  u16* Qh = p;  p += nX;
  u16* Kh = p;  p += nX;
  u16* Vtr = p; p += nX;
  float* cost = (float*)p;
  float* sint = cost + (size_t)S * 32;

  // weights-only cvt (activations converted inside the QKV GEMMs)
  CvtJobs jobs;
  jobs.src[0] = W_q; jobs.src[1] = W_k; jobs.src[2] = W_v; jobs.src[3] = W_o;
  jobs.src[4] = W_o; jobs.src[5] = W_o; jobs.src[6] = W_o;   // unused
  jobs.dst[0] = wq; jobs.dst[1] = wk; jobs.dst[2] = wv; jobs.dst[3] = wo;
  jobs.dst[4] = wo; jobs.dst[5] = wo; jobs.dst[6] = wo;      // unused
  const int w4 = (int)(nW / 4);
  jobs.pref[0] = 0; jobs.pref[1] = w4; jobs.pref[2] = 2 * w4;
  jobs.pref[3] = 3 * w4; jobs.pref[4] = 4 * w4;
  jobs.pref[5] = 4 * w4; jobs.pref[6] = 4 * w4; jobs.pref[7] = 4 * w4;
  cvt_all<<<512, 256, 0, stream>>>(jobs, 4 * w4);

  rope_tables<<<(S * 32 + 255) / 256, 256, 0, stream>>>(cost, sint, S);

  const int gblocks = (BS / 128) * (D / 128);   // 512
  gemm_fused<0, 1><<<gblocks, 256, 0, stream>>>(query, wq, b_q, Qh,  cost, sint, BS, D, D, S);
  gemm_fused<1, 1><<<gblocks, 256, 0, stream>>>(key,   wk, b_k, Kh,  cost, sint, BS, D, D, S);
  gemm_fused<2, 1><<<gblocks, 256, 0, stream>>>(value, wv, b_v, Vtr, cost, sint, BS, D, D, S);

  // 1024 blocks: LPT order (big stiles first), bh&7 -> XCD partition
  attn_kernel<<<(S / 128) * B * H, 256, 0, stream>>>(Qh, Kh, Vtr, ctx, B, H, S);

  gemm_fused<3, 0><<<gblocks, 256, 0, stream>>>(ctx, wo, b_o, d_out, cost, sint, BS, D, D, S);
}

// Round 11
// 337.708 us; speedup vs baseline: 1.1918x; 1.1918x over previous
//
#include <hip/hip_runtime.h>
#include <hip/hip_bf16.h>
#include <cstdint>
#include <cstddef>

// ---------------------------------------------------------------------------
// MultiHeadAttention fused pipeline, bf16 MFMA compute.
//   B=4, S=2048, D=1024, H=16, dk=64
// Stages:
//   1. cvt_all: q/k/v activations + 4 weights fp32->bf16 (one kernel)
//   2. rope tables [S][32]
//   3. gemm_fused<0/1/2>: QKV projection GEMMs, 512-thread blocks
//      (8 waves 4Mx2N -> 16 waves/CU), fused epilogues:
//        0: +bias -> RoPE -> *0.125*log2e -> Qh [bh][s][dk]
//        1: +bias -> RoPE ->                Kh [bh][s][dk]
//        2: +bias -> transpose           -> Vtr [bh][dk][s]
//   4. flash attention (causal, swapped-operand MFMA, LPT-ordered 1024
//      blocks, double-buffered staging, defer-max) -> ctx bf16 [B*S, D]
//   5. gemm_fused<3>: out = ctx @ W_o^T + b_o (f32, token-major)
// ---------------------------------------------------------------------------

typedef __attribute__((ext_vector_type(8))) short short8;   // 8 x bf16 (4 VGPR)
typedef __attribute__((ext_vector_type(4))) float f32x4;    // MFMA C/D frag
typedef unsigned short u16;

#define SCALE_Q 0.18033688011112042f   /* 0.125 * log2(e): scores in exp2 domain */

__device__ __forceinline__ u16 f2bf(float f) {
  __hip_bfloat16 h = __float2bfloat16(f);
  return *reinterpret_cast<u16*>(&h);
}
__device__ __forceinline__ float bf2f(short bits) {
  unsigned int u = ((unsigned int)(u16)bits) << 16;
  return __uint_as_float(u);
}
__device__ __forceinline__ void gload_lds16(const void* g, void* l) {
  __builtin_amdgcn_global_load_lds(
      (const __attribute__((address_space(1))) void*)g,
      (__attribute__((address_space(3))) void*)l, 16, 0, 0);
}
__device__ __forceinline__ f32x4 max4(f32x4 a, f32x4 b) {
  f32x4 r;
  r[0] = fmaxf(a[0], b[0]); r[1] = fmaxf(a[1], b[1]);
  r[2] = fmaxf(a[2], b[2]); r[3] = fmaxf(a[3], b[3]);
  return r;
}

// ---------------------------------------------------------------------------
// 1. one-shot fp32 -> bf16 convert, 7 jobs
// ---------------------------------------------------------------------------
struct CvtJobs {
  const float* src[7];
  u16* dst[7];
  int pref[8];   // prefix sums in float4 units
};

__global__ void cvt_all(CvtJobs jobs, int total4) {
  const int stride = gridDim.x * blockDim.x;
  for (int i = blockIdx.x * blockDim.x + threadIdx.x; i < total4; i += stride) {
    int j = 0;
#pragma unroll
    for (int t = 1; t < 7; ++t) j += (i >= jobs.pref[t]);
    const int off = i - jobs.pref[j];
    const float4 v = ((const float4*)jobs.src[j])[off];
    ushort4 o;
    o.x = f2bf(v.x); o.y = f2bf(v.y); o.z = f2bf(v.z); o.w = f2bf(v.w);
    ((ushort4*)jobs.dst[j])[off] = o;
  }
}

// ---------------------------------------------------------------------------
// 2. RoPE tables: cos/sin(s * 10000^(-i/32)), i in [0,32)
// ---------------------------------------------------------------------------
__global__ void rope_tables(float* __restrict__ cost, float* __restrict__ sint, int S) {
  const int idx = blockIdx.x * blockDim.x + threadIdx.x;
  if (idx >= S * 32) return;
  const int s = idx >> 5, i = idx & 31;
  const float invf = powf(10000.0f, -(float)i * (1.0f / 32.0f));
  const float ang = (float)s * invf;
  cost[idx] = cosf(ang);
  sint[idx] = sinf(ang);
}

// ---------------------------------------------------------------------------
// 3/5. GEMM  C = A[M,K] @ Bt[N,K]^T + bias, fused epilogues.
//   512 threads, 8 waves in 4M x 2N grid (wave-tile 32 rows x 64 cols) ->
//   2 blocks/CU = 16 waves/CU (vs 8 at 256 threads: round-10 lesson, the
//   128x128 4-wave config ran at half the m97-structure MfmaUtil).
//   128x128 tile, BK=64, 16x16x32 MFMA, XOR-swizzled LDS via pre-swizzled
//   global source, global_load_lds staging (m151: beats reg-staging).
//   MODE 0: Q -> RoPE -> *SCALE_Q -> [bh][s][64]
//   MODE 1: K -> RoPE ->            [bh][s][64]
//   MODE 2: V -> transpose ->       [bh][64][s]
//   MODE 3: f32 token-major [M][N]  (output projection)
//   1D grid 512, XCD-chunked remap. Hardcoded: S=2048, H=16, dk=64.
// ---------------------------------------------------------------------------
template<int MODE>
__global__ __launch_bounds__(512, 4)
void gemm_fused(const u16* __restrict__ A, const u16* __restrict__ Bt,
                const float* __restrict__ bias, void* __restrict__ Cout,
                const float* __restrict__ cost, const float* __restrict__ sint,
                int M, int N, int K, int S) {
  __shared__ u16 As[128 * 64];
  __shared__ u16 Bs[128 * 64];
  const int tid = threadIdx.x;
  const int wid = tid >> 6;              // 0..7
  const int lane = tid & 63;
  const int g = lane >> 4, c = lane & 15;

  // XCD-chunked remap (hw round-robins linear id over 8 XCDs)
  const int xcd = blockIdx.x & 7;
  const int slot = blockIdx.x >> 3;
  const int mPerX = (M >> 7) >> 3;               // 8
  const int m0 = (xcd * mPerX + (slot % mPerX)) << 7;
  const int n0 = (slot / mPerX) << 7;

  const int wr = wid >> 1;               // 0..3, 32-row strips
  const int wc = wid & 1;                // 0..1, 64-col strips

  f32x4 acc[2][4];
#pragma unroll
  for (int i = 0; i < 2; ++i)
#pragma unroll
    for (int j = 0; j < 4; ++j) acc[i][j] = (f32x4)(0.0f);

  const int kIters = K >> 6;
  for (int kt = 0; kt < kIters; ++kt) {
    const int k0 = kt << 6;
    // stage both 128x64 bf16 tiles: 1024 chunks each, 2 issues x 512 thr
#pragma unroll
    for (int i = 0; i < 2; ++i) {
      const int chunk = i * 512 + tid;
      const int row = chunk >> 3;
      const int scz = (chunk & 7) ^ (row & 7);       // inverse-swizzled source
      gload_lds16(A + (size_t)(m0 + row) * K + (k0 + scz * 8),
                  (char*)As + (size_t)(i * 512 + (wid << 6)) * 16);
      gload_lds16(Bt + (size_t)(n0 + row) * K + (k0 + scz * 8),
                  (char*)Bs + (size_t)(i * 512 + (wid << 6)) * 16);
    }
    __syncthreads();
#pragma unroll
    for (int ks = 0; ks < 2; ++ks) {
      short8 af[2], bfr[4];
#pragma unroll
      for (int mi = 0; mi < 2; ++mi) {
        const int row = wr * 32 + mi * 16 + c;
        const int cch = (g + ks * 4) ^ (row & 7);    // swizzled read
        af[mi] = *(const short8*)((const char*)As + row * 128 + cch * 16);
      }
#pragma unroll
      for (int ni = 0; ni < 4; ++ni) {
        const int row = wc * 64 + ni * 16 + c;
        const int cch = (g + ks * 4) ^ (row & 7);
        bfr[ni] = *(const short8*)((const char*)Bs + row * 128 + cch * 16);
      }
#pragma unroll
      for (int mi = 0; mi < 2; ++mi)
#pragma unroll
        for (int ni = 0; ni < 4; ++ni)
          acc[mi][ni] = __builtin_amdgcn_mfma_f32_16x16x32_bf16(af[mi], bfr[ni], acc[mi][ni], 0, 0, 0);
    }
    __syncthreads();
  }

  float bv[4];
#pragma unroll
  for (int ni = 0; ni < 4; ++ni) bv[ni] = bias[n0 + wc * 64 + ni * 16 + c];

  // C/D layout: col = lane&15, row = (lane>>4)*4 + reg  [m89/m91 verified]
  if (MODE == 3) {
#pragma unroll
    for (int mi = 0; mi < 2; ++mi)
#pragma unroll
      for (int ni = 0; ni < 4; ++ni)
#pragma unroll
        for (int r = 0; r < 4; ++r) {
          const int row = m0 + wr * 32 + mi * 16 + g * 4 + r;
          const int col = n0 + wc * 64 + ni * 16 + c;
          ((float*)Cout)[(size_t)row * N + col] = acc[mi][ni][r] + bv[ni];
        }
  } else if (MODE == 2) {
    // V: +bias, transpose to [bh][64][S]; 4 consecutive tokens -> ushort4
#pragma unroll
    for (int mi = 0; mi < 2; ++mi) {
      const int row_base = m0 + wr * 32 + mi * 16 + g * 4;
      const int s = row_base & 2047;            // S = 2048
      const int b = row_base >> 11;
#pragma unroll
      for (int ni = 0; ni < 4; ++ni) {
        const int col = n0 + wc * 64 + ni * 16 + c;
        const int h = col >> 6;
        const int d = ni * 16 + c;              // col & 63
        ushort4 w;
        w.x = f2bf(acc[mi][ni][0] + bv[ni]);
        w.y = f2bf(acc[mi][ni][1] + bv[ni]);
        w.z = f2bf(acc[mi][ni][2] + bv[ni]);
        w.w = f2bf(acc[mi][ni][3] + bv[ni]);
        *(ushort4*)((u16*)Cout + ((size_t)(b * 16 + h) * 64 + d) * (size_t)S + s) = w;
      }
    }
  } else {
    // Q/K: +bias, RoPE on pairs (ni, ni+2) == (d, d+32), Q also *SCALE_Q
#pragma unroll
    for (int mi = 0; mi < 2; ++mi)
#pragma unroll
      for (int pair = 0; pair < 2; ++pair) {
        const int d_lo = pair * 16 + c;         // in [0,32) -> freq index i
        const int col_lo = n0 + wc * 64 + d_lo;
        const int h = col_lo >> 6;
#pragma unroll
        for (int r = 0; r < 4; ++r) {
          const int row = m0 + wr * 32 + mi * 16 + g * 4 + r;
          const int s = row & 2047;             // S = 2048
          const int b = row >> 11;
          const float co = cost[s * 32 + d_lo];
          const float si = sint[s * 32 + d_lo];
          const float vlo = acc[mi][pair][r] + bv[pair];
          const float vhi = acc[mi][pair + 2][r] + bv[pair + 2];
          float olo = vlo * co - vhi * si;
          float ohi = vhi * co + vlo * si;
          if (MODE == 0) { olo *= SCALE_Q; ohi *= SCALE_Q; }
          u16* dst = (u16*)Cout + ((size_t)(b * 16 + h) * S + s) * 64 + d_lo;
          dst[0]  = f2bf(olo);
          dst[32] = f2bf(ohi);
        }
      }
  }
}

// ---------------------------------------------------------------------------
// 4. causal flash attention, v4 (unchanged from round 10): LPT-ordered
//   independent blocks. 1024 blocks, each ONE 128-q supertile.
//   stile = 15 - (id>>6) -> big stiles dispatch first (LPT makespan, no
//   id->CU mapping assumption). bh = id&63 -> stable head->XCD L2 partition.
//   4 waves x 32 q-rows. Swapped-operand MFMA, 2-phase double-buffered
//   staging, defer-max THR=8, setprio around MFMA clusters.
// ---------------------------------------------------------------------------
__global__ __launch_bounds__(256, 4)
void attn_kernel(const u16* __restrict__ Qh, const u16* __restrict__ Kh,
                 const u16* __restrict__ Vt, u16* __restrict__ ctx,
                 int B, int H, int S) {
  __shared__ u16 KV[2][2][64 * 64];   // [buf][K=0/V=1], 32 KiB
  __shared__ u16 Ps[4][16 * 64];      // per-wave P tile (reused per qf), 8 KiB
  const int tid = threadIdx.x, wid = tid >> 6, lane = tid & 63;
  const int g = lane >> 4, c = lane & 15;

  const int id = blockIdx.x;             // 0..1023
  const int stile = 15 - (id >> 6);      // LPT: big stiles first
  const int bh = id & 63;                // bh&7 == id&7 -> XCD partition

  const int b = bh >> 4, h = bh & 15;
  const int D = H * 64;

  const size_t baseQK = (size_t)bh * S * 64;
  const size_t baseV  = (size_t)bh * 64 * S;

  const int q0 = stile * 128;
  const int KT = 2 * stile + 2;          // causal k-tiles for this supertile
  const int q0w = q0 + wid * 32;
  const int ktl = (q0w + 31) >> 6;       // wave's last (partial) k-tile
  const int qg0 = q0w + c, qg1 = q0w + 16 + c;

  // Q B-frags, hoisted: lane holds Q[q0w+qf*16+c][32*ks+8*g .. +8)
  short8 qB[2][2];
#pragma unroll
  for (int qf = 0; qf < 2; ++qf)
#pragma unroll
    for (int ks = 0; ks < 2; ++ks)
      qB[qf][ks] = *(const short8*)(Qh + baseQK +
                     (size_t)(q0w + qf * 16 + c) * 64 + ks * 32 + g * 8);

  float m_r[2], l_r[2];
  m_r[0] = m_r[1] = -__builtin_inff();
  l_r[0] = l_r[1] = 0.0f;
  f32x4 o[4][2];
#pragma unroll
  for (int df = 0; df < 4; ++df) { o[df][0] = (f32x4)(0.0f); o[df][1] = (f32x4)(0.0f); }

  auto stage = [&](int buf, int kt) {
#pragma unroll
    for (int i = 0; i < 2; ++i) {
      const int chunk = i * 256 + tid;
      const int row = chunk >> 3;
      const int scz = (chunk & 7) ^ (row & 7);
      gload_lds16(Kh + baseQK + (size_t)(kt * 64 + row) * 64 + scz * 8,
                  (char*)&KV[buf][0][0] + (size_t)(i * 256 + (wid << 6)) * 16);
      gload_lds16(Vt + baseV + (size_t)row * S + (kt * 64 + scz * 8),
                  (char*)&KV[buf][1][0] + (size_t)(i * 256 + (wid << 6)) * 16);
    }
  };

  stage(0, 0);
  __syncthreads();
  int cur = 0;
  for (int kt = 0; kt < KT; ++kt) {
    if (kt + 1 < KT) stage(cur ^ 1, kt + 1);   // 2-phase prefetch
    if (kt <= ktl) {                            // wave-uniform causal skip
      const char* Kb = (const char*)&KV[cur][0][0];
      const char* Vb = (const char*)&KV[cur][1][0];

      // QK^T (swapped): sc[kf][qf] = D[k=kf*16+4g+r][q=qf*16+c]
      f32x4 sc[4][2];
#pragma unroll
      for (int kf = 0; kf < 4; ++kf) { sc[kf][0] = (f32x4)(0.0f); sc[kf][1] = (f32x4)(0.0f); }
      __builtin_amdgcn_s_setprio(1);
#pragma unroll
      for (int ks = 0; ks < 2; ++ks) {
        short8 kA[4];
#pragma unroll
        for (int kf = 0; kf < 4; ++kf) {
          const int row = kf * 16 + c;
          kA[kf] = *(const short8*)(Kb + row * 128 + (((g + 4 * ks) ^ (row & 7))) * 16);
        }
#pragma unroll
        for (int kf = 0; kf < 4; ++kf) {
          sc[kf][0] = __builtin_amdgcn_mfma_f32_16x16x32_bf16(kA[kf], qB[0][ks], sc[kf][0], 0, 0, 0);
          sc[kf][1] = __builtin_amdgcn_mfma_f32_16x16x32_bf16(kA[kf], qB[1][ks], sc[kf][1], 0, 0, 0);
        }
      }
      __builtin_amdgcn_s_setprio(0);

      if (kt == ktl) {   // only the last tile is causally partial
#pragma unroll
        for (int kf = 0; kf < 4; ++kf)
#pragma unroll
          for (int r = 0; r < 4; ++r) {
            const int kg = kt * 64 + kf * 16 + 4 * g + r;
            if (kg > qg0) sc[kf][0][r] = -__builtin_inff();
            if (kg > qg1) sc[kf][1][r] = -__builtin_inff();
          }
      }

      u16* Pw = &Ps[wid][0];
      short8 pB[2][2];
#pragma unroll
      for (int qf = 0; qf < 2; ++qf) {
        // row max: 15 in-lane + 2 shfl (lanes c,c+16,c+32,c+48 share q)
        f32x4 mm = max4(max4(sc[0][qf], sc[1][qf]), max4(sc[2][qf], sc[3][qf]));
        float pm = fmaxf(fmaxf(mm[0], mm[1]), fmaxf(mm[2], mm[3]));
        pm = fmaxf(pm, __shfl_xor(pm, 16));
        pm = fmaxf(pm, __shfl_xor(pm, 32));
        // defer-max (THR=8 in exp2 domain -> P bounded by 256)
        if (__any(pm > m_r[qf] + 8.0f)) {
          const float mn = fmaxf(m_r[qf], pm);
          const float rs = __builtin_exp2f(m_r[qf] - mn);
          m_r[qf] = mn; l_r[qf] *= rs;
#pragma unroll
          for (int df = 0; df < 4; ++df) o[df][qf] *= rs;
        }
        f32x4 ps4 = (f32x4)(0.0f);
#pragma unroll
        for (int kf = 0; kf < 4; ++kf) {
          f32x4 pv;
#pragma unroll
          for (int r = 0; r < 4; ++r) pv[r] = __builtin_exp2f(sc[kf][qf][r] - m_r[qf]);
          sc[kf][qf] = pv;
          ps4 += pv;
        }
        float psum = (ps4[0] + ps4[1]) + (ps4[2] + ps4[3]);
        psum += __shfl_xor(psum, 16);
        psum += __shfl_xor(psum, 32);
        l_r[qf] += psum;

        // P -> per-wave LDS (b64 writes, swizzled), then P^T B-frags
#pragma unroll
        for (int kf = 0; kf < 4; ++kf) {
          ushort4 pk;
          pk.x = f2bf(sc[kf][qf][0]); pk.y = f2bf(sc[kf][qf][1]);
          pk.z = f2bf(sc[kf][qf][2]); pk.w = f2bf(sc[kf][qf][3]);
          *(ushort4*)((char*)Pw + c * 128 +
                      (((2 * kf + (g >> 1)) ^ (c & 7))) * 16 + 8 * (g & 1)) = pk;
        }
#pragma unroll
        for (int ks = 0; ks < 2; ++ks)
          pB[qf][ks] = *(const short8*)((const char*)Pw + c * 128 +
                                        (((g + 4 * ks) ^ (c & 7))) * 16);
      }

      // PV (swapped): o[df][qf] = D[d=df*16+4g+r][q=qf*16+c]
      __builtin_amdgcn_s_setprio(1);
#pragma unroll
      for (int ks = 0; ks < 2; ++ks)
#pragma unroll
        for (int df = 0; df < 4; ++df) {
          const int row = df * 16 + c;
          const short8 va = *(const short8*)(Vb + row * 128 + (((g + 4 * ks) ^ (row & 7))) * 16);
          o[df][0] = __builtin_amdgcn_mfma_f32_16x16x32_bf16(va, pB[0][ks], o[df][0], 0, 0, 0);
          o[df][1] = __builtin_amdgcn_mfma_f32_16x16x32_bf16(va, pB[1][ks], o[df][1], 0, 0, 0);
        }
      __builtin_amdgcn_s_setprio(0);
    }
    __syncthreads();
    cur ^= 1;
  }

  // epilogue: O^T -> ctx token-major; lane owns rows q (qf*16+c), d runs of 4
#pragma unroll
  for (int qf = 0; qf < 2; ++qf) {
    const float inv = 1.0f / l_r[qf];
    u16* rowp = ctx + (size_t)(b * S + q0w + qf * 16 + c) * D + h * 64;
#pragma unroll
    for (int df = 0; df < 4; ++df) {
      ushort4 w;
      w.x = f2bf(o[df][qf][0] * inv); w.y = f2bf(o[df][qf][1] * inv);
      w.z = f2bf(o[df][qf][2] * inv); w.w = f2bf(o[df][qf][3] * inv);
      *(ushort4*)(rowp + df * 16 + 4 * g) = w;
    }
  }
}

// ---------------------------------------------------------------------------
extern "C" void kernel_launch(void* const* d_in, const int* in_sizes, int n_in,
                              void* d_out, int out_size, void* d_ws, size_t ws_size,
                              hipStream_t stream) {
  const float* query = (const float*)d_in[0];
  const float* key   = (const float*)d_in[1];
  const float* value = (const float*)d_in[2];
  const float* W_q = (const float*)d_in[3];
  const float* b_q = (const float*)d_in[4];
  const float* W_k = (const float*)d_in[5];
  const float* b_k = (const float*)d_in[6];
  const float* W_v = (const float*)d_in[7];
  const float* b_v = (const float*)d_in[8];
  const float* W_o = (const float*)d_in[9];
  const float* b_o = (const float*)d_in[10];

  const int D = 1024, H = 16, S = 2048;
  const int BS = in_sizes[0] / D;          // B * S = 8192
  const int B = BS / S;

  const size_t nX = (size_t)BS * D;        // 8.4M elems
  const size_t nW = (size_t)D * D;
  u16* p = (u16*)d_ws;
  u16* xq = p;  p += nX;
  u16* xk = p;  p += nX;
  u16* xv = p;  p += nX;
  u16* wq = p;  p += nW;
  u16* wk = p;  p += nW;
  u16* wv = p;  p += nW;
  u16* wo = p;  p += nW;
  u16* Qh = p;  p += nX;
  u16* Kh = p;  p += nX;
  u16* Vtr = p; p += nX;
  float* cost = (float*)p;
  float* sint = cost + (size_t)S * 32;
  u16* ctx = xq;   // alias: xq dead after Q-projection GEMM

  // one-shot cvt of all 7 fp32 buffers (activations + weights)
  CvtJobs jobs;
  jobs.src[0] = query; jobs.src[1] = key; jobs.src[2] = value;
  jobs.src[3] = W_q;   jobs.src[4] = W_k; jobs.src[5] = W_v; jobs.src[6] = W_o;
  jobs.dst[0] = xq; jobs.dst[1] = xk; jobs.dst[2] = xv;
  jobs.dst[3] = wq; jobs.dst[4] = wk; jobs.dst[5] = wv; jobs.dst[6] = wo;
  const int a4 = (int)(nX / 4), w4 = (int)(nW / 4);
  jobs.pref[0] = 0;
  jobs.pref[1] = a4;     jobs.pref[2] = 2 * a4; jobs.pref[3] = 3 * a4;
  jobs.pref[4] = 3 * a4 + w4;     jobs.pref[5] = 3 * a4 + 2 * w4;
  jobs.pref[6] = 3 * a4 + 3 * w4; jobs.pref[7] = 3 * a4 + 4 * w4;
  cvt_all<<<2048, 256, 0, stream>>>(jobs, jobs.pref[7]);

  rope_tables<<<(S * 32 + 255) / 256, 256, 0, stream>>>(cost, sint, S);

  const int gblocks = (BS / 128) * (D / 128);   // 512
  gemm_fused<0><<<gblocks, 512, 0, stream>>>(xq, wq, b_q, Qh,  cost, sint, BS, D, D, S);
  gemm_fused<1><<<gblocks, 512, 0, stream>>>(xk, wk, b_k, Kh,  cost, sint, BS, D, D, S);
  gemm_fused<2><<<gblocks, 512, 0, stream>>>(xv, wv, b_v, Vtr, cost, sint, BS, D, D, S);

  // 1024 blocks: LPT order (big stiles first), bh&7 -> XCD partition
  attn_kernel<<<(S / 128) * B * H, 256, 0, stream>>>(Qh, Kh, Vtr, ctx, B, H, S);

  gemm_fused<3><<<gblocks, 512, 0, stream>>>(ctx, wo, b_o, d_out, cost, sint, BS, D, D, S);
}

// Round 12
// 323.279 us; speedup vs baseline: 1.2450x; 1.0446x over previous
//
#include <hip/hip_runtime.h>
#include <hip/hip_bf16.h>
#include <cstdint>
#include <cstddef>

// ---------------------------------------------------------------------------
// MultiHeadAttention fused pipeline, bf16 MFMA compute.
//   B=4, S=2048, D=1024, H=16, dk=64
// Stages:
//   1. cvt_all: q/k/v activations + 4 weights fp32->bf16 (one kernel)
//   2. rope tables [S][32]
//   3. qkv_gemm: ONE 1536-block launch, mode=blockIdx.x>>9 selects:
//        0: +bias -> RoPE -> *0.125*log2e -> Qh [bh][s][dk]
//        1: +bias -> RoPE ->                Kh [bh][s][dk]
//        2: +bias -> transpose           -> Vtr [bh][dk][s]
//      256-thr 4-wave 128x128 body, __launch_bounds__(256,3) -> 3 blocks/CU
//      (m97-parity occupancy; round-11 lesson: (256,2) let VGPR>170 ->
//      2 blocks/CU -> half the cross-block overlap).
//   4. flash attention (causal, swapped-operand MFMA, LPT-ordered 1024
//      blocks, double-buffered staging, defer-max) -> ctx bf16 [B*S, D]
//   5. gemm_fused<3>: out = ctx @ W_o^T + b_o (f32, token-major)
// ---------------------------------------------------------------------------

typedef __attribute__((ext_vector_type(8))) short short8;   // 8 x bf16 (4 VGPR)
typedef __attribute__((ext_vector_type(4))) float f32x4;    // MFMA C/D frag
typedef unsigned short u16;

#define SCALE_Q 0.18033688011112042f   /* 0.125 * log2(e): scores in exp2 domain */

__device__ __forceinline__ u16 f2bf(float f) {
  __hip_bfloat16 h = __float2bfloat16(f);
  return *reinterpret_cast<u16*>(&h);
}
__device__ __forceinline__ float bf2f(short bits) {
  unsigned int u = ((unsigned int)(u16)bits) << 16;
  return __uint_as_float(u);
}
__device__ __forceinline__ void gload_lds16(const void* g, void* l) {
  __builtin_amdgcn_global_load_lds(
      (const __attribute__((address_space(1))) void*)g,
      (__attribute__((address_space(3))) void*)l, 16, 0, 0);
}
__device__ __forceinline__ f32x4 max4(f32x4 a, f32x4 b) {
  f32x4 r;
  r[0] = fmaxf(a[0], b[0]); r[1] = fmaxf(a[1], b[1]);
  r[2] = fmaxf(a[2], b[2]); r[3] = fmaxf(a[3], b[3]);
  return r;
}

// ---------------------------------------------------------------------------
// 1. one-shot fp32 -> bf16 convert, 7 jobs
// ---------------------------------------------------------------------------
struct CvtJobs {
  const float* src[7];
  u16* dst[7];
  int pref[8];   // prefix sums in float4 units
};

__global__ void cvt_all(CvtJobs jobs, int total4) {
  const int stride = gridDim.x * blockDim.x;
  for (int i = blockIdx.x * blockDim.x + threadIdx.x; i < total4; i += stride) {
    int j = 0;
#pragma unroll
    for (int t = 1; t < 7; ++t) j += (i >= jobs.pref[t]);
    const int off = i - jobs.pref[j];
    const float4 v = ((const float4*)jobs.src[j])[off];
    ushort4 o;
    o.x = f2bf(v.x); o.y = f2bf(v.y); o.z = f2bf(v.z); o.w = f2bf(v.w);
    ((ushort4*)jobs.dst[j])[off] = o;
  }
}

// ---------------------------------------------------------------------------
// 2. RoPE tables: cos/sin(s * 10000^(-i/32)), i in [0,32)
// ---------------------------------------------------------------------------
__global__ void rope_tables(float* __restrict__ cost, float* __restrict__ sint, int S) {
  const int idx = blockIdx.x * blockDim.x + threadIdx.x;
  if (idx >= S * 32) return;
  const int s = idx >> 5, i = idx & 31;
  const float invf = powf(10000.0f, -(float)i * (1.0f / 32.0f));
  const float ang = (float)s * invf;
  cost[idx] = cosf(ang);
  sint[idx] = sinf(ang);
}

// ---------------------------------------------------------------------------
// 3/5. GEMM body  C = A[M,K] @ Bt[N,K]^T + bias, fused epilogues.
//   256 threads, 4 waves 2x2 (wave-tile 64x64, acc 4x4) — the verified R6
//   body. 128x128 tile, BK=64, 16x16x32 MFMA, XOR-swizzled LDS via
//   pre-swizzled global source, global_load_lds staging.
//   MODE 0: Q -> RoPE -> *SCALE_Q -> [bh][s][64]
//   MODE 1: K -> RoPE ->            [bh][s][64]
//   MODE 2: V -> transpose ->       [bh][64][s]
//   MODE 3: f32 token-major [M][N]  (output projection)
//   bid in [0,512): XCD-chunked remap. Hardcoded: S=2048, H=16, dk=64.
// ---------------------------------------------------------------------------
template<int MODE>
__device__ __forceinline__
void gemm_body(int bid, const u16* __restrict__ A, const u16* __restrict__ Bt,
               const float* __restrict__ bias, void* __restrict__ Cout,
               const float* __restrict__ cost, const float* __restrict__ sint,
               int M, int N, int K, int S, u16* As, u16* Bs) {
  const int tid = threadIdx.x;
  const int wid = tid >> 6;
  const int lane = tid & 63;
  const int g = lane >> 4, c = lane & 15;

  // XCD-chunked remap (hw round-robins linear id over 8 XCDs)
  const int xcd = bid & 7;
  const int slot = bid >> 3;
  const int mPerX = (M >> 7) >> 3;               // 8
  const int m0 = (xcd * mPerX + (slot % mPerX)) << 7;
  const int n0 = (slot / mPerX) << 7;

  const int wr = wid >> 1, wc = wid & 1;

  f32x4 acc[4][4];
#pragma unroll
  for (int i = 0; i < 4; ++i)
#pragma unroll
    for (int j = 0; j < 4; ++j) acc[i][j] = (f32x4)(0.0f);

  const int kIters = K >> 6;
  for (int kt = 0; kt < kIters; ++kt) {
    const int k0 = kt << 6;
#pragma unroll
    for (int i = 0; i < 4; ++i) {
      const int chunk = i * 256 + tid;
      const int row = chunk >> 3;
      const int scz = (chunk & 7) ^ (row & 7);       // inverse-swizzled source
      gload_lds16(A + (size_t)(m0 + row) * K + (k0 + scz * 8),
                  (char*)As + (size_t)(i * 256 + (wid << 6)) * 16);
      gload_lds16(Bt + (size_t)(n0 + row) * K + (k0 + scz * 8),
                  (char*)Bs + (size_t)(i * 256 + (wid << 6)) * 16);
    }
    __syncthreads();
#pragma unroll
    for (int ks = 0; ks < 2; ++ks) {
      short8 af[4], bfr[4];
#pragma unroll
      for (int mi = 0; mi < 4; ++mi) {
        const int row = wr * 64 + mi * 16 + c;
        const int cch = (g + ks * 4) ^ (row & 7);    // swizzled read
        af[mi] = *(const short8*)((const char*)As + row * 128 + cch * 16);
      }
#pragma unroll
      for (int ni = 0; ni < 4; ++ni) {
        const int row = wc * 64 + ni * 16 + c;
        const int cch = (g + ks * 4) ^ (row & 7);
        bfr[ni] = *(const short8*)((const char*)Bs + row * 128 + cch * 16);
      }
#pragma unroll
      for (int mi = 0; mi < 4; ++mi)
#pragma unroll
        for (int ni = 0; ni < 4; ++ni)
          acc[mi][ni] = __builtin_amdgcn_mfma_f32_16x16x32_bf16(af[mi], bfr[ni], acc[mi][ni], 0, 0, 0);
    }
    __syncthreads();
  }

  float bv[4];
#pragma unroll
  for (int ni = 0; ni < 4; ++ni) bv[ni] = bias[n0 + wc * 64 + ni * 16 + c];

  // C/D layout: col = lane&15, row = (lane>>4)*4 + reg  [m89/m91 verified]
  if (MODE == 3) {
#pragma unroll
    for (int mi = 0; mi < 4; ++mi)
#pragma unroll
      for (int ni = 0; ni < 4; ++ni)
#pragma unroll
        for (int r = 0; r < 4; ++r) {
          const int row = m0 + wr * 64 + mi * 16 + g * 4 + r;
          const int col = n0 + wc * 64 + ni * 16 + c;
          ((float*)Cout)[(size_t)row * N + col] = acc[mi][ni][r] + bv[ni];
        }
  } else if (MODE == 2) {
    // V: +bias, transpose to [bh][64][S]; 4 consecutive tokens -> ushort4
#pragma unroll
    for (int mi = 0; mi < 4; ++mi) {
      const int row_base = m0 + wr * 64 + mi * 16 + g * 4;
      const int s = row_base & 2047;            // S = 2048
      const int b = row_base >> 11;
#pragma unroll
      for (int ni = 0; ni < 4; ++ni) {
        const int col = n0 + wc * 64 + ni * 16 + c;
        const int h = col >> 6;
        const int d = ni * 16 + c;              // col & 63
        ushort4 w;
        w.x = f2bf(acc[mi][ni][0] + bv[ni]);
        w.y = f2bf(acc[mi][ni][1] + bv[ni]);
        w.z = f2bf(acc[mi][ni][2] + bv[ni]);
        w.w = f2bf(acc[mi][ni][3] + bv[ni]);
        *(ushort4*)((u16*)Cout + ((size_t)(b * 16 + h) * 64 + d) * (size_t)S + s) = w;
      }
    }
  } else {
    // Q/K: +bias, RoPE on pairs (ni, ni+2) == (d, d+32), Q also *SCALE_Q
#pragma unroll
    for (int mi = 0; mi < 4; ++mi)
#pragma unroll
      for (int pair = 0; pair < 2; ++pair) {
        const int d_lo = pair * 16 + c;         // in [0,32) -> freq index i
        const int col_lo = n0 + wc * 64 + d_lo;
        const int h = col_lo >> 6;
#pragma unroll
        for (int r = 0; r < 4; ++r) {
          const int row = m0 + wr * 64 + mi * 16 + g * 4 + r;
          const int s = row & 2047;             // S = 2048
          const int b = row >> 11;
          const float co = cost[s * 32 + d_lo];
          const float si = sint[s * 32 + d_lo];
          const float vlo = acc[mi][pair][r] + bv[pair];
          const float vhi = acc[mi][pair + 2][r] + bv[pair + 2];
          float olo = vlo * co - vhi * si;
          float ohi = vhi * co + vlo * si;
          if (MODE == 0) { olo *= SCALE_Q; ohi *= SCALE_Q; }
          u16* dst = (u16*)Cout + ((size_t)(b * 16 + h) * S + s) * 64 + d_lo;
          dst[0]  = f2bf(olo);
          dst[32] = f2bf(ohi);
        }
      }
  }
}

// merged QKV: 1536 blocks, mode = blockIdx.x >> 9 (block-uniform branch)
__global__ __launch_bounds__(256, 3)
void qkv_gemm(const u16* __restrict__ xq, const u16* __restrict__ xk,
              const u16* __restrict__ xv,
              const u16* __restrict__ wq, const u16* __restrict__ wk,
              const u16* __restrict__ wv,
              const float* __restrict__ bq, const float* __restrict__ bk,
              const float* __restrict__ bv,
              u16* __restrict__ Qh, u16* __restrict__ Kh, u16* __restrict__ Vtr,
              const float* __restrict__ cost, const float* __restrict__ sint,
              int M, int N, int K, int S) {
  __shared__ u16 As[128 * 64];
  __shared__ u16 Bs[128 * 64];
  const int mode = blockIdx.x >> 9;
  const int bid = blockIdx.x & 511;
  if (mode == 0)
    gemm_body<0>(bid, xq, wq, bq, Qh, cost, sint, M, N, K, S, As, Bs);
  else if (mode == 1)
    gemm_body<1>(bid, xk, wk, bk, Kh, cost, sint, M, N, K, S, As, Bs);
  else
    gemm_body<2>(bid, xv, wv, bv, Vtr, cost, sint, M, N, K, S, As, Bs);
}

// output projection (f32 out)
__global__ __launch_bounds__(256, 3)
void o_gemm(const u16* __restrict__ A, const u16* __restrict__ Bt,
            const float* __restrict__ bias, float* __restrict__ Cout,
            int M, int N, int K, int S) {
  __shared__ u16 As[128 * 64];
  __shared__ u16 Bs[128 * 64];
  gemm_body<3>(blockIdx.x, A, Bt, bias, Cout, nullptr, nullptr, M, N, K, S, As, Bs);
}

// ---------------------------------------------------------------------------
// 4. causal flash attention, v4 (unchanged): LPT-ordered independent blocks.
//   1024 blocks, each ONE 128-q supertile. stile = 15-(id>>6) -> big stiles
//   dispatch first. bh = id&63 -> stable head->XCD L2 partition.
//   4 waves x 32 q-rows. Swapped-operand MFMA, 2-phase double-buffered
//   staging, defer-max THR=8, setprio around MFMA clusters.
// ---------------------------------------------------------------------------
__global__ __launch_bounds__(256, 4)
void attn_kernel(const u16* __restrict__ Qh, const u16* __restrict__ Kh,
                 const u16* __restrict__ Vt, u16* __restrict__ ctx,
                 int B, int H, int S) {
  __shared__ u16 KV[2][2][64 * 64];   // [buf][K=0/V=1], 32 KiB
  __shared__ u16 Ps[4][16 * 64];      // per-wave P tile (reused per qf), 8 KiB
  const int tid = threadIdx.x, wid = tid >> 6, lane = tid & 63;
  const int g = lane >> 4, c = lane & 15;

  const int id = blockIdx.x;             // 0..1023
  const int stile = 15 - (id >> 6);      // LPT: big stiles first
  const int bh = id & 63;                // bh&7 == id&7 -> XCD partition

  const int b = bh >> 4, h = bh & 15;
  const int D = H * 64;

  const size_t baseQK = (size_t)bh * S * 64;
  const size_t baseV  = (size_t)bh * 64 * S;

  const int q0 = stile * 128;
  const int KT = 2 * stile + 2;          // causal k-tiles for this supertile
  const int q0w = q0 + wid * 32;
  const int ktl = (q0w + 31) >> 6;       // wave's last (partial) k-tile
  const int qg0 = q0w + c, qg1 = q0w + 16 + c;

  // Q B-frags, hoisted: lane holds Q[q0w+qf*16+c][32*ks+8*g .. +8)
  short8 qB[2][2];
#pragma unroll
  for (int qf = 0; qf < 2; ++qf)
#pragma unroll
    for (int ks = 0; ks < 2; ++ks)
      qB[qf][ks] = *(const short8*)(Qh + baseQK +
                     (size_t)(q0w + qf * 16 + c) * 64 + ks * 32 + g * 8);

  float m_r[2], l_r[2];
  m_r[0] = m_r[1] = -__builtin_inff();
  l_r[0] = l_r[1] = 0.0f;
  f32x4 o[4][2];
#pragma unroll
  for (int df = 0; df < 4; ++df) { o[df][0] = (f32x4)(0.0f); o[df][1] = (f32x4)(0.0f); }

  auto stage = [&](int buf, int kt) {
#pragma unroll
    for (int i = 0; i < 2; ++i) {
      const int chunk = i * 256 + tid;
      const int row = chunk >> 3;
      const int scz = (chunk & 7) ^ (row & 7);
      gload_lds16(Kh + baseQK + (size_t)(kt * 64 + row) * 64 + scz * 8,
                  (char*)&KV[buf][0][0] + (size_t)(i * 256 + (wid << 6)) * 16);
      gload_lds16(Vt + baseV + (size_t)row * S + (kt * 64 + scz * 8),
                  (char*)&KV[buf][1][0] + (size_t)(i * 256 + (wid << 6)) * 16);
    }
  };

  stage(0, 0);
  __syncthreads();
  int cur = 0;
  for (int kt = 0; kt < KT; ++kt) {
    if (kt + 1 < KT) stage(cur ^ 1, kt + 1);   // 2-phase prefetch
    if (kt <= ktl) {                            // wave-uniform causal skip
      const char* Kb = (const char*)&KV[cur][0][0];
      const char* Vb = (const char*)&KV[cur][1][0];

      // QK^T (swapped): sc[kf][qf] = D[k=kf*16+4g+r][q=qf*16+c]
      f32x4 sc[4][2];
#pragma unroll
      for (int kf = 0; kf < 4; ++kf) { sc[kf][0] = (f32x4)(0.0f); sc[kf][1] = (f32x4)(0.0f); }
      __builtin_amdgcn_s_setprio(1);
#pragma unroll
      for (int ks = 0; ks < 2; ++ks) {
        short8 kA[4];
#pragma unroll
        for (int kf = 0; kf < 4; ++kf) {
          const int row = kf * 16 + c;
          kA[kf] = *(const short8*)(Kb + row * 128 + (((g + 4 * ks) ^ (row & 7))) * 16);
        }
#pragma unroll
        for (int kf = 0; kf < 4; ++kf) {
          sc[kf][0] = __builtin_amdgcn_mfma_f32_16x16x32_bf16(kA[kf], qB[0][ks], sc[kf][0], 0, 0, 0);
          sc[kf][1] = __builtin_amdgcn_mfma_f32_16x16x32_bf16(kA[kf], qB[1][ks], sc[kf][1], 0, 0, 0);
        }
      }
      __builtin_amdgcn_s_setprio(0);

      if (kt == ktl) {   // only the last tile is causally partial
#pragma unroll
        for (int kf = 0; kf < 4; ++kf)
#pragma unroll
          for (int r = 0; r < 4; ++r) {
            const int kg = kt * 64 + kf * 16 + 4 * g + r;
            if (kg > qg0) sc[kf][0][r] = -__builtin_inff();
            if (kg > qg1) sc[kf][1][r] = -__builtin_inff();
          }
      }

      u16* Pw = &Ps[wid][0];
      short8 pB[2][2];
#pragma unroll
      for (int qf = 0; qf < 2; ++qf) {
        // row max: 15 in-lane + 2 shfl (lanes c,c+16,c+32,c+48 share q)
        f32x4 mm = max4(max4(sc[0][qf], sc[1][qf]), max4(sc[2][qf], sc[3][qf]));
        float pm = fmaxf(fmaxf(mm[0], mm[1]), fmaxf(mm[2], mm[3]));
        pm = fmaxf(pm, __shfl_xor(pm, 16));
        pm = fmaxf(pm, __shfl_xor(pm, 32));
        // defer-max (THR=8 in exp2 domain -> P bounded by 256)
        if (__any(pm > m_r[qf] + 8.0f)) {
          const float mn = fmaxf(m_r[qf], pm);
          const float rs = __builtin_exp2f(m_r[qf] - mn);
          m_r[qf] = mn; l_r[qf] *= rs;
#pragma unroll
          for (int df = 0; df < 4; ++df) o[df][qf] *= rs;
        }
        f32x4 ps4 = (f32x4)(0.0f);
#pragma unroll
        for (int kf = 0; kf < 4; ++kf) {
          f32x4 pv;
#pragma unroll
          for (int r = 0; r < 4; ++r) pv[r] = __builtin_exp2f(sc[kf][qf][r] - m_r[qf]);
          sc[kf][qf] = pv;
          ps4 += pv;
        }
        float psum = (ps4[0] + ps4[1]) + (ps4[2] + ps4[3]);
        psum += __shfl_xor(psum, 16);
        psum += __shfl_xor(psum, 32);
        l_r[qf] += psum;

        // P -> per-wave LDS (b64 writes, swizzled), then P^T B-frags
#pragma unroll
        for (int kf = 0; kf < 4; ++kf) {
          ushort4 pk;
          pk.x = f2bf(sc[kf][qf][0]); pk.y = f2bf(sc[kf][qf][1]);
          pk.z = f2bf(sc[kf][qf][2]); pk.w = f2bf(sc[kf][qf][3]);
          *(ushort4*)((char*)Pw + c * 128 +
                      (((2 * kf + (g >> 1)) ^ (c & 7))) * 16 + 8 * (g & 1)) = pk;
        }
#pragma unroll
        for (int ks = 0; ks < 2; ++ks)
          pB[qf][ks] = *(const short8*)((const char*)Pw + c * 128 +
                                        (((g + 4 * ks) ^ (c & 7))) * 16);
      }

      // PV (swapped): o[df][qf] = D[d=df*16+4g+r][q=qf*16+c]
      __builtin_amdgcn_s_setprio(1);
#pragma unroll
      for (int ks = 0; ks < 2; ++ks)
#pragma unroll
        for (int df = 0; df < 4; ++df) {
          const int row = df * 16 + c;
          const short8 va = *(const short8*)(Vb + row * 128 + (((g + 4 * ks) ^ (row & 7))) * 16);
          o[df][0] = __builtin_amdgcn_mfma_f32_16x16x32_bf16(va, pB[0][ks], o[df][0], 0, 0, 0);
          o[df][1] = __builtin_amdgcn_mfma_f32_16x16x32_bf16(va, pB[1][ks], o[df][1], 0, 0, 0);
        }
      __builtin_amdgcn_s_setprio(0);
    }
    __syncthreads();
    cur ^= 1;
  }

  // epilogue: O^T -> ctx token-major; lane owns rows q (qf*16+c), d runs of 4
#pragma unroll
  for (int qf = 0; qf < 2; ++qf) {
    const float inv = 1.0f / l_r[qf];
    u16* rowp = ctx + (size_t)(b * S + q0w + qf * 16 + c) * D + h * 64;
#pragma unroll
    for (int df = 0; df < 4; ++df) {
      ushort4 w;
      w.x = f2bf(o[df][qf][0] * inv); w.y = f2bf(o[df][qf][1] * inv);
      w.z = f2bf(o[df][qf][2] * inv); w.w = f2bf(o[df][qf][3] * inv);
      *(ushort4*)(rowp + df * 16 + 4 * g) = w;
    }
  }
}

// ---------------------------------------------------------------------------
extern "C" void kernel_launch(void* const* d_in, const int* in_sizes, int n_in,
                              void* d_out, int out_size, void* d_ws, size_t ws_size,
                              hipStream_t stream) {
  const float* query = (const float*)d_in[0];
  const float* key   = (const float*)d_in[1];
  const float* value = (const float*)d_in[2];
  const float* W_q = (const float*)d_in[3];
  const float* b_q = (const float*)d_in[4];
  const float* W_k = (const float*)d_in[5];
  const float* b_k = (const float*)d_in[6];
  const float* W_v = (const float*)d_in[7];
  const float* b_v = (const float*)d_in[8];
  const float* W_o = (const float*)d_in[9];
  const float* b_o = (const float*)d_in[10];

  const int D = 1024, H = 16, S = 2048;
  const int BS = in_sizes[0] / D;          // B * S = 8192
  const int B = BS / S;

  const size_t nX = (size_t)BS * D;        // 8.4M elems
  const size_t nW = (size_t)D * D;
  u16* p = (u16*)d_ws;
  u16* xq = p;  p += nX;
  u16* xk = p;  p += nX;
  u16* xv = p;  p += nX;
  u16* wq = p;  p += nW;
  u16* wk = p;  p += nW;
  u16* wv = p;  p += nW;
  u16* wo = p;  p += nW;
  u16* Qh = p;  p += nX;
  u16* Kh = p;  p += nX;
  u16* Vtr = p; p += nX;
  float* cost = (float*)p;
  float* sint = cost + (size_t)S * 32;
  u16* ctx = xq;   // alias: xq dead after Q-projection GEMM

  // one-shot cvt of all 7 fp32 buffers (activations + weights)
  CvtJobs jobs;
  jobs.src[0] = query; jobs.src[1] = key; jobs.src[2] = value;
  jobs.src[3] = W_q;   jobs.src[4] = W_k; jobs.src[5] = W_v; jobs.src[6] = W_o;
  jobs.dst[0] = xq; jobs.dst[1] = xk; jobs.dst[2] = xv;
  jobs.dst[3] = wq; jobs.dst[4] = wk; jobs.dst[5] = wv; jobs.dst[6] = wo;
  const int a4 = (int)(nX / 4), w4 = (int)(nW / 4);
  jobs.pref[0] = 0;
  jobs.pref[1] = a4;     jobs.pref[2] = 2 * a4; jobs.pref[3] = 3 * a4;
  jobs.pref[4] = 3 * a4 + w4;     jobs.pref[5] = 3 * a4 + 2 * w4;
  jobs.pref[6] = 3 * a4 + 3 * w4; jobs.pref[7] = 3 * a4 + 4 * w4;
  cvt_all<<<2048, 256, 0, stream>>>(jobs, jobs.pref[7]);

  rope_tables<<<(S * 32 + 255) / 256, 256, 0, stream>>>(cost, sint, S);

  // merged QKV projections: 3 x 512 blocks in one launch
  qkv_gemm<<<3 * 512, 256, 0, stream>>>(xq, xk, xv, wq, wk, wv,
                                        b_q, b_k, b_v, Qh, Kh, Vtr,
                                        cost, sint, BS, D, D, S);

  // 1024 blocks: LPT order (big stiles first), bh&7 -> XCD partition
  attn_kernel<<<(S / 128) * B * H, 256, 0, stream>>>(Qh, Kh, Vtr, ctx, B, H, S);

  o_gemm<<<512, 256, 0, stream>>>(ctx, wo, b_o, (float*)d_out, BS, D, D, S);
}